// Round 11
// baseline (190.872 us; speedup 1.0000x reference)
//
#include <hip/hip_runtime.h>
#include <hip/hip_bf16.h>

// Problem constants
#define NN 4096
#define FIN 512
#define HID 256
#define NH 4
#define DD 64
#define NCLS 64

typedef short bf16x8 __attribute__((ext_vector_type(8)));
typedef float f32x4 __attribute__((ext_vector_type(4)));
typedef unsigned int u32x4 __attribute__((ext_vector_type(4)));

__device__ __forceinline__ unsigned fbits(float x) {
    return __builtin_bit_cast(unsigned, x);
}
__device__ __forceinline__ unsigned short f2bf_rne(float x) {
    unsigned u = fbits(x);
    unsigned r = (u + 0x7fffu + ((u >> 16) & 1u)) >> 16;
    return (unsigned short)r;
}

// pack 8 f32 -> bf16x8 fragment (truncate). R6-verified path.
__device__ __forceinline__ bf16x8 pack8(const float* wv) {
    u32x4 au;
#pragma unroll
    for (int t = 0; t < 4; ++t)
        au[t] = (fbits(wv[2 * t]) >> 16) | (fbits(wv[2 * t + 1]) & 0xffff0000u);
    return __builtin_bit_cast(bf16x8, au);
}

__device__ __forceinline__ bf16x8 ones_frag() {
    u32x4 au = {0x3f803f80u, 0x3f803f80u, 0x3f803f80u, 0x3f803f80u};
    return __builtin_bit_cast(bf16x8, au);
}

// ---------------------------------------------------------------------------
// Inline MFMA layout probe (R6-verified method, now per-wave, no globals).
// Recovers logical (row, col) of D element (lane, reg) for our fragment
// construction convention via two one-hot MFMAs.
// ---------------------------------------------------------------------------
__device__ __forceinline__ void compute_probe(int m, int quad, int* pi, int* pn) {
    float xv[8], yv[8];
#pragma unroll
    for (int e = 0; e < 8; ++e) {
        xv[e] = (quad == 0 && e == 0) ? (float)(m + 1) : 0.f;
        yv[e] = (quad == 0 && e == 0) ? 1.f : 0.f;
    }
    bf16x8 x1 = pack8(xv), y1 = pack8(yv);
#pragma unroll
    for (int e = 0; e < 8; ++e) {
        xv[e] = (quad == 0 && e == 0) ? 1.f : 0.f;
        yv[e] = (quad == 0 && e == 0) ? (float)(m + 1) : 0.f;
    }
    bf16x8 x2 = pack8(xv), y2 = pack8(yv);
    f32x4 d1 = {}, d2 = {};
    d1 = __builtin_amdgcn_mfma_f32_16x16x32_bf16(x1, y1, d1, 0, 0, 0);
    d2 = __builtin_amdgcn_mfma_f32_16x16x32_bf16(x2, y2, d2, 0, 0, 0);
#pragma unroll
    for (int r = 0; r < 4; ++r) {
        pi[r] = min(15, max(0, (int)d1[r] - 1));
        pn[r] = min(15, max(0, (int)d2[r] - 1));
    }
}

// ---------------------------------------------------------------------------
// Adjacency -> bitmask (4 elems/thread, coalesced).
// ---------------------------------------------------------------------------
__global__ __launch_bounds__(256) void adj_bitmask(const int* __restrict__ Adj,
                                                   unsigned* __restrict__ Adjb) {
    const size_t base = (size_t)blockIdx.x * 1024;
    const int tid = threadIdx.x, lane = tid & 63;
#pragma unroll
    for (int c = 0; c < 4; ++c) {
        size_t gid = base + c * 256 + tid;
        int v = Adj[gid];
        unsigned long long bm = __ballot(v > 0);
        if ((lane & 31) == 0)
            Adjb[gid >> 5] = (unsigned)((lane & 32) ? (bm >> 32) : bm);
    }
}

// ---------------------------------------------------------------------------
// Transpose + f32->bf16:  In[R][C] f32 -> OutT[C][R] bf16. (weights only)
// ---------------------------------------------------------------------------
template <int R, int C>
__global__ __launch_bounds__(256) void transpose_cvt(const float* __restrict__ In,
                                                     unsigned short* __restrict__ OutT) {
    __shared__ float t[32][33];
    const int tid = threadIdx.x;
    const int r0 = blockIdx.y * 32, c0 = blockIdx.x * 32;
    const int rl = tid >> 3, cg = tid & 7;
    float4 v = *(const float4*)&In[(size_t)(r0 + rl) * C + c0 + cg * 4];
    t[rl][cg * 4 + 0] = v.x; t[rl][cg * 4 + 1] = v.y;
    t[rl][cg * 4 + 2] = v.z; t[rl][cg * 4 + 3] = v.w;
    __syncthreads();
    const int cl = tid >> 3, rg = tid & 7;
    ushort4 o;
    o.x = f2bf_rne(t[rg * 4 + 0][cl]);
    o.y = f2bf_rne(t[rg * 4 + 1][cl]);
    o.z = f2bf_rne(t[rg * 4 + 2][cl]);
    o.w = f2bf_rne(t[rg * 4 + 3][cl]);
    *(ushort4*)&OutT[(size_t)(c0 + cl) * R + r0 + rg * 4] = o;
}

// ---------------------------------------------------------------------------
// Fused GEMM head: 16x64 tile, 4-wave k-split, 1-step prefetch pipeline.
// Epilogue: HT (bf16 transposed), src score, EP[j]={exp(sd), exp(0.2 sd)}.
// ---------------------------------------------------------------------------
template <int K, bool ABF>
__global__ __launch_bounds__(256) void gemm_head(
    const void* __restrict__ Ap,
    const unsigned short* __restrict__ WT,
    const float* __restrict__ a_src, const float* __restrict__ a_dst,
    unsigned short* __restrict__ HT,
    float* __restrict__ ssr,
    float* __restrict__ EP)
{
    __shared__ float accx[4][16][65];
    __shared__ unsigned short hbf[16][64];
    const int tid = threadIdx.x;
    const int lane = tid & 63, sp = tid >> 6;
    const int m = lane & 15, quad = lane >> 4;
    const int hh = blockIdx.x, i0 = blockIdx.y * 16;
    const int n0 = hh * 64;
    int pi[4], pn[4];
    compute_probe(m, quad, pi, pn);
    f32x4 acc[4] = {};
    constexpr int KS = K / 128;

    bf16x8 a[2], b[2][4];
    auto load_a = [&](int ks) -> bf16x8 {
        const int kb = sp * (K / 4) + ks * 32 + quad * 8;
        if (ABF) {
            return *(const bf16x8*)((const unsigned short*)Ap + (size_t)(i0 + m) * K + kb);
        } else {
            const float* Af = (const float*)Ap + (size_t)(i0 + m) * K + kb;
            float4 a0 = *(const float4*)Af;
            float4 a1 = *(const float4*)(Af + 4);
            float av8[8] = {a0.x, a0.y, a0.z, a0.w, a1.x, a1.y, a1.z, a1.w};
            u32x4 au;
#pragma unroll
            for (int t = 0; t < 4; ++t) {
                unsigned lo = (unsigned)f2bf_rne(av8[2 * t]);
                unsigned hi = (unsigned)f2bf_rne(av8[2 * t + 1]) << 16;
                au[t] = lo | hi;
            }
            return __builtin_bit_cast(bf16x8, au);
        }
    };
    a[0] = load_a(0);
#pragma unroll
    for (int nt = 0; nt < 4; ++nt) {
        const int kb = sp * (K / 4) + quad * 8;
        b[0][nt] = *(const bf16x8*)&WT[(size_t)(n0 + nt * 16 + m) * K + kb];
    }
#pragma unroll
    for (int ks = 0; ks < KS; ++ks) {
        const int cur = ks & 1, nxt = cur ^ 1;
        if (ks + 1 < KS) {
            a[nxt] = load_a(ks + 1);
            const int kb = sp * (K / 4) + (ks + 1) * 32 + quad * 8;
#pragma unroll
            for (int nt = 0; nt < 4; ++nt)
                b[nxt][nt] = *(const bf16x8*)&WT[(size_t)(n0 + nt * 16 + m) * K + kb];
        }
#pragma unroll
        for (int nt = 0; nt < 4; ++nt)
            acc[nt] = __builtin_amdgcn_mfma_f32_16x16x32_bf16(a[cur], b[cur][nt], acc[nt], 0, 0, 0);
    }
#pragma unroll
    for (int nt = 0; nt < 4; ++nt)
#pragma unroll
        for (int r = 0; r < 4; ++r)
            accx[sp][pi[r]][nt * 16 + pn[r]] = acc[nt][r];
    __syncthreads();

    const int row = tid >> 4, cg = tid & 15;
    float ps = 0.f, pd = 0.f;
#pragma unroll
    for (int c4 = 0; c4 < 4; ++c4) {
        int col = cg * 4 + c4;
        float val = accx[0][row][col] + accx[1][row][col] +
                    accx[2][row][col] + accx[3][row][col];
        ps += val * a_src[n0 + col];
        pd += val * a_dst[n0 + col];
        hbf[row][col] = f2bf_rne(val);
    }
#pragma unroll
    for (int o = 8; o >= 1; o >>= 1) {
        ps += __shfl_xor(ps, o, 64);
        pd += __shfl_xor(pd, o, 64);
    }
    if (cg == 0) {
        int node = i0 + row;
        ssr[hh * NN + node] = ps;
        EP[(size_t)(hh * NN + node) * 2 + 0] = __expf(pd);
        EP[(size_t)(hh * NN + node) * 2 + 1] = __expf(0.2f * pd);
    }
    __syncthreads();
    const int c = tid >> 2, rq = tid & 3;
    ushort4 o4;
    o4.x = hbf[rq * 4 + 0][c];
    o4.y = hbf[rq * 4 + 1][c];
    o4.z = hbf[rq * 4 + 2][c];
    o4.w = hbf[rq * 4 + 3][c];
    *(ushort4*)&HT[(size_t)(n0 + c) * NN + i0 + rq * 4] = o4;
}

// ---------------------------------------------------------------------------
// Multi-i-tile pipelined attention core.  Per j-step: 8 shared loads
// (4 EP f32x4 + 4 HT bf16x8), IT tiles of weight-gen + 4 MFMAs each, plus
// one ones-MFMA per tile for the denominator (exact sum of the same bf16 w).
// ---------------------------------------------------------------------------
template <int IT, int NSTEP>
__device__ __forceinline__ void attn_core_mt(
    const unsigned short* __restrict__ htb,
    const unsigned* __restrict__ Adjb,
    const float* __restrict__ ssh,
    const float* __restrict__ eph,
    const int i0, const int jbase, const int m, const int quad,
    f32x4 (&acc)[IT][4], f32x4 (&accd)[IT])
{
    const bf16x8 ones = ones_frag();
    const unsigned* mrow[IT];
    float E1i[IT], E2i[IT];
#pragma unroll
    for (int t = 0; t < IT; ++t) {
        float ss = ssh[i0 + t * 16 + m];
        E1i[t] = __expf(ss);
        E2i[t] = __expf(0.2f * ss);
        mrow[t] = Adjb + (size_t)(i0 + t * 16 + m) * 128 + (jbase >> 5);
    }
    u32x4 mwb[2][IT];
    f32x4 ep[2][4];
    bf16x8 bf[2][4];
#pragma unroll
    for (int t = 0; t < IT; ++t) mwb[0][t] = *(const u32x4*)mrow[t];
    {
        const int kb = jbase + quad * 8;
        const float* e = eph + 2 * kb;
#pragma unroll
        for (int v = 0; v < 4; ++v) ep[0][v] = *(const f32x4*)(e + 4 * v);
#pragma unroll
        for (int nt = 0; nt < 4; ++nt)
            bf[0][nt] = *(const bf16x8*)&htb[(size_t)(nt * 16 + m) * NN + kb];
    }
#pragma unroll
    for (int s = 0; s < NSTEP; ++s) {
        const int cur = s & 1, nxt = cur ^ 1;
        if (s + 1 < NSTEP) {
            const int kb = jbase + (s + 1) * 32 + quad * 8;
            const float* e = eph + 2 * kb;
#pragma unroll
            for (int v = 0; v < 4; ++v) ep[nxt][v] = *(const f32x4*)(e + 4 * v);
#pragma unroll
            for (int nt = 0; nt < 4; ++nt)
                bf[nxt][nt] = *(const bf16x8*)&htb[(size_t)(nt * 16 + m) * NN + kb];
        }
        if ((s & 3) == 0 && s + 4 < NSTEP) {
#pragma unroll
            for (int t = 0; t < IT; ++t)
                mwb[((s >> 2) + 1) & 1][t] =
                    *(const u32x4*)(mrow[t] + (s >> 2) * 4 + 4);
        }
#pragma unroll
        for (int t = 0; t < IT; ++t) {
            const unsigned mb = (mwb[(s >> 2) & 1][t][s & 3] >> (quad * 8)) & 0xffu;
            float wv[8];
#pragma unroll
            for (int u = 0; u < 8; ++u) {
                float e1 = ep[cur][u >> 1][(2 * u) & 3];
                float e2 = ep[cur][u >> 1][(2 * u + 1) & 3];
                float w = fmaxf(E1i[t] * e1, E2i[t] * e2);
                wv[u] = ((mb >> u) & 1u) ? w : 0.f;
            }
            bf16x8 av = pack8(wv);
            accd[t] = __builtin_amdgcn_mfma_f32_16x16x32_bf16(av, ones, accd[t], 0, 0, 0);
#pragma unroll
            for (int nt = 0; nt < 4; ++nt)
                acc[t][nt] = __builtin_amdgcn_mfma_f32_16x16x32_bf16(
                    av, bf[cur][nt], acc[t][nt], 0, 0, 0);
        }
    }
}

// ---------------------------------------------------------------------------
// Attention layer 1: grid (NN/64, NH), 512 threads = 8 j-splits of 512;
// 4 i-tiles per wave; single-sync 133 KB LDS epilogue.
// ---------------------------------------------------------------------------
__global__ __launch_bounds__(512, 2) void attn_l1(
    const unsigned short* __restrict__ HT,
    const unsigned* __restrict__ Adjb,
    const float* __restrict__ ssr,
    const float* __restrict__ EP,
    unsigned short* __restrict__ Outb)
{
    __shared__ float accx[4][8][16][65];  // 133 KB
    __shared__ float lx[4][8][16];
    const int tid = threadIdx.x;
    const int lane = tid & 63, sp = tid >> 6;
    const int m = lane & 15, quad = lane >> 4;
    const int i0 = blockIdx.x * 64, hh = blockIdx.y;
    int pi[4], pn[4];
    compute_probe(m, quad, pi, pn);

    const unsigned short* htb = HT + (size_t)(hh * 64) * NN;
    const float* eph = EP + (size_t)hh * NN * 2;
    const float* ssh = ssr + hh * NN;

    f32x4 acc[4][4] = {};
    f32x4 accd[4] = {};
    attn_core_mt<4, 16>(htb, Adjb, ssh, eph, i0, sp * 512, m, quad, acc, accd);

#pragma unroll
    for (int t = 0; t < 4; ++t) {
#pragma unroll
        for (int nt = 0; nt < 4; ++nt)
#pragma unroll
            for (int r = 0; r < 4; ++r)
                accx[t][sp][pi[r]][nt * 16 + pn[r]] = acc[t][nt][r];
#pragma unroll
        for (int r = 0; r < 4; ++r) lx[t][sp][pi[r]] = accd[t][r];
    }
    __syncthreads();

#pragma unroll
    for (int e = 0; e < 8; ++e) {
        int idx = tid + e * 512;
        int t = idx >> 10, row = (idx >> 6) & 15, col = idx & 63;
        float num = 0.f, den = 0.f;
#pragma unroll
        for (int s = 0; s < 8; ++s) {
            num += accx[t][s][row][col];
            den += lx[t][s][row];
        }
        float o = num / den;
        o = (o > 0.f) ? o : (__expf(o) - 1.f);
        Outb[(size_t)(i0 + t * 16 + row) * HID + hh * 64 + col] = f2bf_rne(o);
    }
}

// ---------------------------------------------------------------------------
// Attention layer 2 (H=1): grid NN/16 (full GPU), 512 threads = 8 j-splits
// of 512, 1 i-tile per wave.
// ---------------------------------------------------------------------------
__global__ __launch_bounds__(512, 2) void attn_l2(
    const unsigned short* __restrict__ HT,
    const unsigned* __restrict__ Adjb,
    const float* __restrict__ ssr,
    const float* __restrict__ EP,
    float* __restrict__ Out)
{
    __shared__ float accx[8][16][65];
    __shared__ float lx[8][16];
    const int tid = threadIdx.x;
    const int lane = tid & 63, sp = tid >> 6;
    const int m = lane & 15, quad = lane >> 4;
    const int i0 = blockIdx.x * 16;
    int pi[4], pn[4];
    compute_probe(m, quad, pi, pn);

    f32x4 acc[1][4] = {};
    f32x4 accd[1] = {};
    attn_core_mt<1, 16>(HT, Adjb, ssr, EP, i0, sp * 512, m, quad, acc, accd);

#pragma unroll
    for (int nt = 0; nt < 4; ++nt)
#pragma unroll
        for (int r = 0; r < 4; ++r)
            accx[sp][pi[r]][nt * 16 + pn[r]] = acc[0][nt][r];
#pragma unroll
    for (int r = 0; r < 4; ++r) lx[sp][pi[r]] = accd[0][r];
    __syncthreads();

#pragma unroll
    for (int e = 0; e < 2; ++e) {
        int idx = tid + e * 512;
        int row = idx >> 6, col = idx & 63;
        float num = 0.f, den = 0.f;
#pragma unroll
        for (int s = 0; s < 8; ++s) {
            num += accx[s][row][col];
            den += lx[s][row];
        }
        Out[(size_t)(i0 + row) * NCLS + col] = num / den;
    }
}

// ---------------------------------------------------------------------------
extern "C" void kernel_launch(void* const* d_in, const int* in_sizes, int n_in,
                              void* d_out, int out_size, void* d_ws, size_t ws_size,
                              hipStream_t stream) {
    const float* x      = (const float*)d_in[0];
    const int*   Adj    = (const int*)d_in[1];
    const float* W1     = (const float*)d_in[2];
    const float* a1_src = (const float*)d_in[3];
    const float* a1_dst = (const float*)d_in[4];
    const float* W2     = (const float*)d_in[5];
    const float* a2_src = (const float*)d_in[6];
    const float* a2_dst = (const float*)d_in[7];
    float* out = (float*)d_out;

    float* ws = (float*)d_ws;
    unsigned short* HT1  = (unsigned short*)ws;                    // 524288 f
    unsigned short* HT2  = (unsigned short*)(ws + 524288);         // 131072 f
    unsigned short* h1e  = (unsigned short*)(ws + 655360);         // 524288 f
    unsigned short* WT1  = (unsigned short*)(ws + 1179648);        // 65536 f
    unsigned short* WT2  = (unsigned short*)(ws + 1245184);        // 8192 f
    unsigned*       Adjb = (unsigned*)(ws + 1253376);              // 524288 u32
    float* s1s = ws + 1777664;   // 16384
    float* EP1 = ws + 1794048;   // 32768
    float* s2s = ws + 1826816;   // 4096
    float* EP2 = ws + 1830912;   // 8192

    // Prep
    adj_bitmask<<<dim3(16384), 256, 0, stream>>>(Adj, Adjb);
    transpose_cvt<FIN, HID><<<dim3(HID / 32, FIN / 32), 256, 0, stream>>>(W1, WT1);
    transpose_cvt<HID, NCLS><<<dim3(NCLS / 32, HID / 32), 256, 0, stream>>>(W2, WT2);

    // Layer 1
    gemm_head<FIN, false><<<dim3(NH, NN / 16), 256, 0, stream>>>(
        x, WT1, a1_src, a1_dst, HT1, s1s, EP1);
    attn_l1<<<dim3(NN / 64, NH), 512, 0, stream>>>(HT1, Adjb, s1s, EP1, h1e);

    // Layer 2
    gemm_head<HID, true><<<dim3(1, NN / 16), 256, 0, stream>>>(
        h1e, WT2, a2_src, a2_dst, HT2, s2s, EP2);
    attn_l2<<<dim3(NN / 16), 512, 0, stream>>>(HT2, Adjb, s2s, EP2, out);
}